// Round 2
// baseline (188.008 us; speedup 1.0000x reference)
//
#include <hip/hip_runtime.h>

// Problem constants (from reference)
#define BB 16
#define WW 256
#define SS 512
#define FF 768
#define LL 4
#define EE 256
#define NW (WW - 1)   // 255 words with spans (slot 0 = root, zeros)
#define RPB 2         // rows (b,w) per block; must divide WW

// One block per RPB output rows (same b for all rows since RPB | WW).
// wave 0 (threads 0..63):   copy word-embedding rows (E=256 floats = 64 float4 each)
// waves 1-3 (threads 64..255): each lane owns one float4 column of F=768 for
//   all RPB rows, accumulating softmax(layer_weights)[l] * layers[l,b,s,f]
//   over each span, scaled by gamma/len.
// Fast path len==2 (the dataset's case): all 8 span loads per row issued
// back-to-back before the softmax math -> 16 outstanding vmem loads/lane.
__global__ __launch_bounds__(256) void bert_lexer_fused(
    const int*   __restrict__ word_indices,   // [B, W]
    const int*   __restrict__ span_starts,    // [B, NW]
    const int*   __restrict__ span_ends,      // [B, NW]
    const float* __restrict__ emb_table,      // [V, E]
    const float* __restrict__ layers,         // [L, B, S, F]
    const float* __restrict__ layer_weights,  // [L]
    const float* __restrict__ gamma,          // [1]
    float*       __restrict__ out)            // [B, W, E+F]
{
    const int g   = blockIdx.x;          // 0 .. B*W/RPB - 1
    const int t   = threadIdx.x;
    const int bw0 = g * RPB;
    const int b   = bw0 / WW;            // same b for all RPB rows

    if (t < 64) {
        // ---- word embedding gather: 64 lanes x float4 = 256 floats per row ----
#pragma unroll
        for (int r = 0; r < RPB; ++r) {
            const int bw  = bw0 + r;
            const int idx = word_indices[bw];
            const float4 v = ((const float4*)(emb_table + (size_t)idx * EE))[t];
            ((float4*)(out + (size_t)bw * (EE + FF)))[t] = v;
        }
    } else {
        const int c = t - 64;            // float4 column index in [0, 192)

        // span metadata for all rows (issued first; scalar-ish, L2-resident)
        int st[RPB], ln[RPB];
#pragma unroll
        for (int r = 0; r < RPB; ++r) {
            const int bw = bw0 + r;
            const int w  = bw - b * WW;
            if (w > 0) {
                const int i = b * NW + (w - 1);
                st[r] = span_starts[i];
                ln[r] = span_ends[i] - st[r];
            } else {
                st[r] = 0; ln[r] = 0;    // root slot: zeros
            }
        }

        // softmax(layer_weights) — L=4, redundantly per thread (cycles hidden
        // behind the span loads below)
        const float l0 = layer_weights[0];
        const float l1 = layer_weights[1];
        const float l2 = layer_weights[2];
        const float l3 = layer_weights[3];
        const float m  = fmaxf(fmaxf(l0, l1), fmaxf(l2, l3));
        const float e0 = __expf(l0 - m);
        const float e1 = __expf(l1 - m);
        const float e2 = __expf(l2 - m);
        const float e3 = __expf(l3 - m);
        const float inv = 1.0f / (e0 + e1 + e2 + e3);
        const float wsm[LL] = { e0 * inv, e1 * inv, e2 * inv, e3 * inv };
        const float gv = gamma[0];

#pragma unroll
        for (int r = 0; r < RPB; ++r) {
            float4 acc = make_float4(0.f, 0.f, 0.f, 0.f);
            if (ln[r] == 2) {
                // ---- fast path: 8 independent float4 loads issued up front ----
                float4 v[2 * LL];
#pragma unroll
                for (int l = 0; l < LL; ++l) {
                    const float* base =
                        layers + (((size_t)l * BB + b) * SS + st[r]) * FF;
                    v[2 * l]     = ((const float4*)base)[c];
                    v[2 * l + 1] = ((const float4*)(base + FF))[c];
                }
#pragma unroll
                for (int l = 0; l < LL; ++l) {
                    const float wl = wsm[l];
                    acc.x += wl * (v[2 * l].x + v[2 * l + 1].x);
                    acc.y += wl * (v[2 * l].y + v[2 * l + 1].y);
                    acc.z += wl * (v[2 * l].z + v[2 * l + 1].z);
                    acc.w += wl * (v[2 * l].w + v[2 * l + 1].w);
                }
                const float sc = gv * 0.5f;
                acc.x *= sc; acc.y *= sc; acc.z *= sc; acc.w *= sc;
            } else if (ln[r] > 0) {
                // ---- generic fallback: arbitrary span length ----
                const int en = st[r] + ln[r];
                for (int s = st[r]; s < en; ++s) {
#pragma unroll
                    for (int l = 0; l < LL; ++l) {
                        const float4 v = ((const float4*)(
                            layers + (((size_t)l * BB + b) * SS + s) * FF))[c];
                        acc.x += wsm[l] * v.x;
                        acc.y += wsm[l] * v.y;
                        acc.z += wsm[l] * v.z;
                        acc.w += wsm[l] * v.w;
                    }
                }
                const float sc = gv / (float)ln[r];
                acc.x *= sc; acc.y *= sc; acc.z *= sc; acc.w *= sc;
            }
            // unconditional write: zeros for root slot / empty spans (poison-safe)
            ((float4*)(out + (size_t)(bw0 + r) * (EE + FF) + EE))[c] = acc;
        }
    }
}

extern "C" void kernel_launch(void* const* d_in, const int* in_sizes, int n_in,
                              void* d_out, int out_size, void* d_ws, size_t ws_size,
                              hipStream_t stream) {
    const int*   word_indices  = (const int*)d_in[0];
    const int*   span_starts   = (const int*)d_in[1];
    const int*   span_ends     = (const int*)d_in[2];
    const float* emb_table     = (const float*)d_in[3];
    const float* layers        = (const float*)d_in[4];
    const float* layer_weights = (const float*)d_in[5];
    const float* gamma         = (const float*)d_in[6];
    float*       out           = (float*)d_out;

    dim3 grid(BB * WW / RPB);
    dim3 block(256);
    hipLaunchKernelGGL(bert_lexer_fused, grid, block, 0, stream,
                       word_indices, span_starts, span_ends,
                       emb_table, layers, layer_weights, gamma, out);
}